// Round 1
// baseline (851.948 us; speedup 1.0000x reference)
//
#include <hip/hip_runtime.h>
#include <cmath>

#define NN 50000
#define EE 800000
#define ETOT (EE + NN)
#define NSCAN ((NN + 1023) / 1024)

__device__ __forceinline__ float lrelu(float x){ return x > 0.0f ? x : 0.2f * x; }
__device__ __forceinline__ int bcast_i(int v, int j){ return __builtin_amdgcn_readlane(v, j); }
__device__ __forceinline__ float bcast_f(float v, int j){
  return __uint_as_float(__builtin_amdgcn_readlane(__float_as_uint(v), j));
}

// ---------------- CSR build ----------------
__global__ void k_hist(const int* __restrict__ dst, int* __restrict__ cnt){
  int i = blockIdx.x * 256 + threadIdx.x;
  if (i >= ETOT) return;
  int d = (i < EE) ? dst[i] : (i - EE);
  atomicAdd(&cnt[d], 1);
}

__global__ void k_scan1(const int* __restrict__ cnt, int* __restrict__ part){
  __shared__ int sm[256];
  int b = blockIdx.x, t = threadIdx.x;
  int base = b * 1024 + t * 4;
  int s = 0;
  #pragma unroll
  for (int j = 0; j < 4; j++) if (base + j < NN) s += cnt[base + j];
  sm[t] = s; __syncthreads();
  for (int off = 128; off; off >>= 1){
    if (t < off) sm[t] += sm[t + off];
    __syncthreads();
  }
  if (t == 0) part[b] = sm[0];
}

__global__ void k_scan2(const int* __restrict__ part, int* __restrict__ part2){
  if (threadIdx.x == 0 && blockIdx.x == 0){
    int run = 0;
    for (int i = 0; i < NSCAN; i++){ part2[i] = run; run += part[i]; }
  }
}

__global__ void k_scan3(const int* __restrict__ cnt, const int* __restrict__ part2,
                        int* __restrict__ rowptr){
  __shared__ int sm[256];
  int b = blockIdx.x, t = threadIdx.x;
  int base = b * 1024 + t * 4;
  int v[4]; int s = 0;
  #pragma unroll
  for (int j = 0; j < 4; j++){ v[j] = (base + j < NN) ? cnt[base + j] : 0; s += v[j]; }
  sm[t] = s; __syncthreads();
  for (int off = 1; off < 256; off <<= 1){
    int x = (t >= off) ? sm[t - off] : 0;
    __syncthreads();
    sm[t] += x;
    __syncthreads();
  }
  int run = part2[b] + sm[t] - s;
  #pragma unroll
  for (int j = 0; j < 4; j++){
    if (base + j < NN){ rowptr[base + j] = run; run += v[j]; }
  }
  if (b == 0 && t == 0) rowptr[NN] = ETOT;
}

__global__ void k_scatter(const int* __restrict__ src, const int* __restrict__ dst,
                          const int* __restrict__ rowptr, int* __restrict__ fill,
                          int* __restrict__ csr){
  int i = blockIdx.x * 256 + threadIdx.x;
  if (i >= ETOT) return;
  int s, d;
  if (i < EE){ s = src[i]; d = dst[i]; } else { s = d = i - EE; }
  int pos = rowptr[d] + atomicAdd(&fill[d], 1);
  csr[pos] = s;
}

// ---------------- fp32 tiled GEMM: C[M,N] = A[M,K] @ B[K,N] ----------------
// BM=128, BN=64, BK=16, 256 threads, TM=8, TN=4
__global__ __launch_bounds__(256) void gemm_f32(const float* __restrict__ A,
                                                const float* __restrict__ B,
                                                float* __restrict__ C,
                                                int M, int N, int K){
  __shared__ float As[16][132];
  __shared__ float Bs[16][68];
  const int t = threadIdx.x;
  const int tx = t & 15;        // col group 0..15
  const int ty = t >> 4;        // row group 0..15
  const int m0 = blockIdx.x * 128;
  const int n0 = blockIdx.y * 64;
  float acc[8][4] = {};

  const int arow = t >> 1;            // 0..127
  const int acolb = (t & 1) * 4;      // 0 or 4
  const int brow = t >> 4;            // 0..15
  const int bcol = (t & 15) * 4;      // 0..60

  for (int k0 = 0; k0 < K; k0 += 16){
    #pragma unroll
    for (int l = 0; l < 2; l++){
      int c = acolb + l * 8;
      float4 av = make_float4(0.f, 0.f, 0.f, 0.f);
      if (m0 + arow < M)
        av = *(const float4*)(A + (size_t)(m0 + arow) * K + k0 + c);
      As[c + 0][arow] = av.x; As[c + 1][arow] = av.y;
      As[c + 2][arow] = av.z; As[c + 3][arow] = av.w;
    }
    float4 bv = *(const float4*)(B + (size_t)(k0 + brow) * N + n0 + bcol);
    *(float4*)(&Bs[brow][bcol]) = bv;
    __syncthreads();
    #pragma unroll
    for (int k = 0; k < 16; k++){
      float4 a0 = *(const float4*)(&As[k][ty * 8]);
      float4 a1 = *(const float4*)(&As[k][ty * 8 + 4]);
      float4 b  = *(const float4*)(&Bs[k][tx * 4]);
      float av[8] = {a0.x, a0.y, a0.z, a0.w, a1.x, a1.y, a1.z, a1.w};
      float bw[4] = {b.x, b.y, b.z, b.w};
      #pragma unroll
      for (int i = 0; i < 8; i++)
        #pragma unroll
        for (int j = 0; j < 4; j++)
          acc[i][j] += av[i] * bw[j];
    }
    __syncthreads();
  }
  #pragma unroll
  for (int i = 0; i < 8; i++){
    int m = m0 + ty * 8 + i;
    if (m < M){
      float4 o = make_float4(acc[i][0], acc[i][1], acc[i][2], acc[i][3]);
      *(float4*)(C + (size_t)m * N + n0 + tx * 4) = o;
    }
  }
}

// ---------------- attention logit row-dots ----------------
__global__ __launch_bounds__(256) void k_rowdot128(const float* __restrict__ xs,
                                                   const float* __restrict__ as,
                                                   const float* __restrict__ ad,
                                                   float* __restrict__ ssrc,
                                                   float* __restrict__ sdst){
  int n = (blockIdx.x * 256 + threadIdx.x) >> 6;
  int lane = threadIdx.x & 63;
  if (n >= NN) return;
  float2 v  = *(const float2*)(xs + (size_t)n * 128 + lane * 2);
  float2 a0 = *(const float2*)(as + lane * 2);
  float2 a1 = *(const float2*)(ad + lane * 2);
  float d0 = v.x * a0.x + v.y * a0.y;
  float d1 = v.x * a1.x + v.y * a1.y;
  #pragma unroll
  for (int off = 32; off; off >>= 1){
    d0 += __shfl_xor(d0, off, 64);
    d1 += __shfl_xor(d1, off, 64);
  }
  if (lane == 0){ ssrc[n] = d0; sdst[n] = d1; }
}

__global__ __launch_bounds__(256) void k_rowdot64(const float* __restrict__ xs,
                                                  const float* __restrict__ as,
                                                  const float* __restrict__ ad,
                                                  float* __restrict__ ssrc,
                                                  float* __restrict__ sdst){
  int n = (blockIdx.x * 256 + threadIdx.x) >> 6;
  int lane = threadIdx.x & 63;
  if (n >= NN) return;
  float v = xs[(size_t)n * 64 + lane];
  float d0 = v * as[lane];
  float d1 = v * ad[lane];
  #pragma unroll
  for (int off = 32; off; off >>= 1){
    d0 += __shfl_xor(d0, off, 64);
    d1 += __shfl_xor(d1, off, 64);
  }
  if (lane == 0){ ssrc[n] = d0; sdst[n] = d1; }
}

// ---------------- segment softmax + aggregation (one wave per node) -------
template<int FPL, bool FINAL>
__global__ __launch_bounds__(256) void k_agg(const int* __restrict__ rowptr,
                                             const int* __restrict__ csr,
                                             const float* __restrict__ ssrc,
                                             const float* __restrict__ sdst,
                                             const float* __restrict__ xs,
                                             const float* __restrict__ bias,
                                             float* __restrict__ outp, int ostride){
  int n = (blockIdx.x * 256 + threadIdx.x) >> 6;
  int lane = threadIdx.x & 63;
  if (n >= NN) return;
  int start = rowptr[n], end = rowptr[n + 1];
  float sdn = sdst[n];

  // pass 1: segment max
  float mloc = -3.0e38f;
  for (int e = start + lane; e < end; e += 64){
    float ev = lrelu(ssrc[csr[e]] + sdn);
    mloc = fmaxf(mloc, ev);
  }
  #pragma unroll
  for (int off = 32; off; off >>= 1) mloc = fmaxf(mloc, __shfl_xor(mloc, off, 64));
  float m = mloc;

  // pass 2: denominator
  float sloc = 0.0f;
  for (int e = start + lane; e < end; e += 64){
    float ev = lrelu(ssrc[csr[e]] + sdn);
    sloc += __expf(ev - m);
  }
  #pragma unroll
  for (int off = 32; off; off >>= 1) sloc += __shfl_xor(sloc, off, 64);
  float inv = 1.0f / sloc;

  // pass 3: weighted feature aggregation
  float acc0 = 0.0f, acc1 = 0.0f;
  for (int cb = start; cb < end; cb += 64){
    int e = cb + lane;
    int sl = 0; float w = 0.0f;
    if (e < end){
      sl = csr[e];
      float ev = lrelu(ssrc[sl] + sdn);
      w = __expf(ev - m) * inv;
    }
    int cnt = min(64, end - cb);
    for (int j = 0; j < cnt; j++){
      int s = bcast_i(sl, j);
      float wj = bcast_f(w, j);
      if (FPL == 2){
        float2 v = *(const float2*)(xs + (size_t)s * 128 + lane * 2);
        acc0 += wj * v.x; acc1 += wj * v.y;
      } else {
        float v = xs[(size_t)s * 64 + lane];
        acc0 += wj * v;
      }
    }
  }

  if (FPL == 2){
    float2 bv = *(const float2*)(bias + lane * 2);
    float o0 = lrelu(acc0 + bv.x);
    float o1 = lrelu(acc1 + bv.y);
    *(float2*)(outp + (size_t)n * ostride + lane * 2) = make_float2(o0, o1);
  } else {
    float o = lrelu(acc0 + bias[lane]);
    if (FINAL) o = tanhf(o);
    outp[(size_t)n * ostride + lane] = o;
  }
}

extern "C" void kernel_launch(void* const* d_in, const int* in_sizes, int n_in,
                              void* d_out, int out_size, void* d_ws, size_t ws_size,
                              hipStream_t stream){
  const float* type_emb  = (const float*)d_in[0];
  const int*   edge      = (const int*)d_in[1];
  const float* W         = (const float*)d_in[2];
  const float* att_src   = (const float*)d_in[3];
  const float* att_dst   = (const float*)d_in[4];
  const float* bias      = (const float*)d_in[5];
  const float* W_out     = (const float*)d_in[6];
  const float* att_src_o = (const float*)d_in[7];
  const float* att_dst_o = (const float*)d_in[8];
  const float* bias_o    = (const float*)d_in[9];
  float* out = (float*)d_out;
  (void)in_sizes; (void)n_in; (void)out_size; (void)ws_size;

  char* ws = (char*)d_ws;
  size_t off = 0;
  auto alloc = [&](size_t bytes) -> void* {
    void* p = ws + off;
    off = (off + bytes + 255) & ~(size_t)255;
    return p;
  };
  float* xs   = (float*)alloc((size_t)NN * 128 * 4);   // per-head xs / layer-2 xs2
  float* x1   = (float*)alloc((size_t)NN * 512 * 4);   // layer-1 concat output
  float* ssrc = (float*)alloc((size_t)NN * 4);
  float* sdst = (float*)alloc((size_t)NN * 4);
  int* cnt    = (int*)alloc((size_t)NN * 4);
  int* rowptr = (int*)alloc((size_t)(NN + 1) * 4);
  int* fill   = (int*)alloc((size_t)NN * 4);
  int* csr    = (int*)alloc((size_t)ETOT * 4);
  int* p1     = (int*)alloc((size_t)NSCAN * 4 + 256);
  int* p2     = (int*)alloc((size_t)NSCAN * 4 + 256);

  // ---- CSR build (dst-sorted) ----
  hipMemsetAsync(cnt, 0, (size_t)NN * 4, stream);
  hipMemsetAsync(fill, 0, (size_t)NN * 4, stream);
  k_hist<<<(ETOT + 255) / 256, 256, 0, stream>>>(edge + EE, cnt);
  k_scan1<<<NSCAN, 256, 0, stream>>>(cnt, p1);
  k_scan2<<<1, 64, 0, stream>>>(p1, p2);
  k_scan3<<<NSCAN, 256, 0, stream>>>(cnt, p2, rowptr);
  k_scatter<<<(ETOT + 255) / 256, 256, 0, stream>>>(edge, edge + EE, rowptr, fill, csr);

  // ---- layer 1, per head ----
  for (int h = 0; h < 4; h++){
    gemm_f32<<<dim3(391, 2), 256, 0, stream>>>(type_emb + (size_t)h * NN * 128,
                                               W + (size_t)h * 128 * 128, xs,
                                               NN, 128, 128);
    k_rowdot128<<<12500, 256, 0, stream>>>(xs, att_src + h * 128, att_dst + h * 128, ssrc, sdst);
    k_agg<2, false><<<12500, 256, 0, stream>>>(rowptr, csr, ssrc, sdst, xs,
                                               bias + h * 128, x1 + h * 128, 512);
  }

  // ---- layer 2 ----
  gemm_f32<<<dim3(391, 1), 256, 0, stream>>>(x1, W_out, xs, NN, 64, 512);
  k_rowdot64<<<12500, 256, 0, stream>>>(xs, att_src_o, att_dst_o, ssrc, sdst);
  k_agg<1, true><<<12500, 256, 0, stream>>>(rowptr, csr, ssrc, sdst, xs, bias_o, out, 64);
}

// Round 2
// 518.016 us; speedup vs baseline: 1.6446x; 1.6446x over previous
//
#include <hip/hip_runtime.h>
#include <cmath>

#define NN 50000
#define EE 800000
#define ETOT (EE + NN)
#define NSCAN ((NN + 1023) / 1024)

typedef __bf16 v8bf __attribute__((ext_vector_type(8)));
typedef float f32x4 __attribute__((ext_vector_type(4)));

__device__ __forceinline__ float lrelu(float x){ return x > 0.0f ? x : 0.2f * x; }
__device__ __forceinline__ int bcast_i(int v, int j){ return __builtin_amdgcn_readlane(v, j); }
__device__ __forceinline__ float bcast_f(float v, int j){
  return __uint_as_float(__builtin_amdgcn_readlane(__float_as_uint(v), j));
}
__device__ __forceinline__ unsigned short f2bf_rne(float x){
  unsigned int u = __float_as_uint(x);
  u += 0x7fffu + ((u >> 16) & 1u);
  return (unsigned short)(u >> 16);
}
__device__ __forceinline__ float bf2f(unsigned short b){
  return __uint_as_float(((unsigned int)b) << 16);
}

// ---------------- CSR build ----------------
__global__ void k_hist(const int* __restrict__ dst, int* __restrict__ cnt){
  int i = blockIdx.x * 256 + threadIdx.x;
  if (i >= ETOT) return;
  int d = (i < EE) ? dst[i] : (i - EE);
  atomicAdd(&cnt[d], 1);
}

__global__ void k_scan1(const int* __restrict__ cnt, int* __restrict__ part){
  __shared__ int sm[256];
  int b = blockIdx.x, t = threadIdx.x;
  int base = b * 1024 + t * 4;
  int s = 0;
  #pragma unroll
  for (int j = 0; j < 4; j++) if (base + j < NN) s += cnt[base + j];
  sm[t] = s; __syncthreads();
  for (int off = 128; off; off >>= 1){
    if (t < off) sm[t] += sm[t + off];
    __syncthreads();
  }
  if (t == 0) part[b] = sm[0];
}

__global__ void k_scan2(const int* __restrict__ part, int* __restrict__ part2){
  if (threadIdx.x == 0 && blockIdx.x == 0){
    int run = 0;
    for (int i = 0; i < NSCAN; i++){ part2[i] = run; run += part[i]; }
  }
}

__global__ void k_scan3(const int* __restrict__ cnt, const int* __restrict__ part2,
                        int* __restrict__ rowptr){
  __shared__ int sm[256];
  int b = blockIdx.x, t = threadIdx.x;
  int base = b * 1024 + t * 4;
  int v[4]; int s = 0;
  #pragma unroll
  for (int j = 0; j < 4; j++){ v[j] = (base + j < NN) ? cnt[base + j] : 0; s += v[j]; }
  sm[t] = s; __syncthreads();
  for (int off = 1; off < 256; off <<= 1){
    int x = (t >= off) ? sm[t - off] : 0;
    __syncthreads();
    sm[t] += x;
    __syncthreads();
  }
  int run = part2[b] + sm[t] - s;
  #pragma unroll
  for (int j = 0; j < 4; j++){
    if (base + j < NN){ rowptr[base + j] = run; run += v[j]; }
  }
  if (b == 0 && t == 0) rowptr[NN] = ETOT;
}

__global__ void k_scatter(const int* __restrict__ src, const int* __restrict__ dst,
                          const int* __restrict__ rowptr, int* __restrict__ fill,
                          int* __restrict__ csr){
  int i = blockIdx.x * 256 + threadIdx.x;
  if (i >= ETOT) return;
  int s, d;
  if (i < EE){ s = src[i]; d = dst[i]; } else { s = d = i - EE; }
  int pos = rowptr[d] + atomicAdd(&fill[d], 1);
  csr[pos] = s;
}

// ---------------- weight conversion: fp32 [.,K,N] -> bf16 hi/lo [.,K/8,N,8] ----
__global__ void k_convB(const float* __restrict__ B, unsigned short* __restrict__ bh,
                        unsigned short* __restrict__ bl, int K, int N, int total){
  int i = blockIdx.x * 256 + threadIdx.x;
  if (i >= total) return;
  int per = K * N;
  int h = i / per, rem = i - h * per;
  int k = rem / N, n = rem - k * N;
  float x = B[i];
  unsigned short hb = f2bf_rne(x);
  unsigned short lb = f2bf_rne(x - bf2f(hb));
  size_t o = (size_t)h * per + ((size_t)(k >> 3) * N + n) * 8 + (k & 7);
  bh[o] = hb; bl[o] = lb;
}

// ---------------- split-bf16 MFMA GEMM ----------------
// C[M,BN(head)] = A[M,K] @ B[K,BN]; A fp32 (converted in staging), B preconverted.
// BM=128, BK=32, 256 threads (4 waves, wave w: rows w*32..w*32+31).
template<int BN, int OSTR>
__global__ __launch_bounds__(256) void gemm_split(const float* __restrict__ A,
                                                  const unsigned short* __restrict__ Bh,
                                                  const unsigned short* __restrict__ Bl,
                                                  unsigned short* __restrict__ out,
                                                  int M, int K){
  const int t = threadIdx.x;
  const int wv = t >> 6, lane = t & 63;
  const int m0 = blockIdx.x * 128;
  const int h = blockIdx.y;
  A  += (size_t)h * M * K;
  Bh += (size_t)h * (K >> 3) * BN * 8;
  Bl += (size_t)h * (K >> 3) * BN * 8;
  const int colOff = h * BN;

  __shared__ v8bf sAh[4][128];
  __shared__ v8bf sAl[4][128];
  __shared__ v8bf sBh[4][BN];
  __shared__ v8bf sBl[4][BN];

  f32x4 acc[2][BN / 16];
  #pragma unroll
  for (int i = 0; i < 2; i++)
    #pragma unroll
    for (int j = 0; j < BN / 16; j++){
      f32x4 z = {0.f, 0.f, 0.f, 0.f};
      acc[i][j] = z;
    }

  const int mRow = t & 127;
  const int kh = (t >> 7) * 16;
  const bool valid = (m0 + mRow) < M;
  const int q = lane >> 4, lm = lane & 15;

  for (int k0 = 0; k0 < K; k0 += 32){
    // ---- stage A (fp32 -> hi/lo bf16, layout [k8][m][8]) ----
    const float* ap = A + (size_t)(m0 + mRow) * K + k0 + kh;
    float4 v0, v1, v2, v3;
    if (valid){
      v0 = *(const float4*)(ap);
      v1 = *(const float4*)(ap + 4);
      v2 = *(const float4*)(ap + 8);
      v3 = *(const float4*)(ap + 12);
    } else {
      v0 = v1 = v2 = v3 = make_float4(0.f, 0.f, 0.f, 0.f);
    }
    #pragma unroll
    for (int g = 0; g < 2; g++){
      float xv[8];
      if (g == 0){ xv[0]=v0.x; xv[1]=v0.y; xv[2]=v0.z; xv[3]=v0.w; xv[4]=v1.x; xv[5]=v1.y; xv[6]=v1.z; xv[7]=v1.w; }
      else       { xv[0]=v2.x; xv[1]=v2.y; xv[2]=v2.z; xv[3]=v2.w; xv[4]=v3.x; xv[5]=v3.y; xv[6]=v3.z; xv[7]=v3.w; }
      union { v8bf v; unsigned short u[8]; } H, L;
      #pragma unroll
      for (int i = 0; i < 8; i++){
        unsigned short hb = f2bf_rne(xv[i]);
        H.u[i] = hb;
        L.u[i] = f2bf_rne(xv[i] - bf2f(hb));
      }
      int k8 = (kh >> 3) + g;
      sAh[k8][mRow] = H.v;
      sAl[k8][mRow] = L.v;
    }
    // ---- stage B (bulk copy, already tiled) ----
    {
      const v8bf* gh = (const v8bf*)Bh + (size_t)(k0 >> 3) * BN;
      const v8bf* gl = (const v8bf*)Bl + (size_t)(k0 >> 3) * BN;
      v8bf* dh = &sBh[0][0];
      v8bf* dl = &sBl[0][0];
      #pragma unroll
      for (int i = t; i < 4 * BN; i += 256){ dh[i] = gh[i]; dl[i] = gl[i]; }
    }
    __syncthreads();
    // ---- MFMA ----
    v8bf ah[2], al[2];
    #pragma unroll
    for (int rt = 0; rt < 2; rt++){
      int m = wv * 32 + rt * 16 + lm;
      ah[rt] = sAh[q][m];
      al[rt] = sAl[q][m];
    }
    #pragma unroll
    for (int ct = 0; ct < BN / 16; ct++){
      v8bf bh = sBh[q][ct * 16 + lm];
      v8bf bl = sBl[q][ct * 16 + lm];
      #pragma unroll
      for (int rt = 0; rt < 2; rt++){
        acc[rt][ct] = __builtin_amdgcn_mfma_f32_16x16x32_bf16(ah[rt], bh, acc[rt][ct], 0, 0, 0);
        acc[rt][ct] = __builtin_amdgcn_mfma_f32_16x16x32_bf16(ah[rt], bl, acc[rt][ct], 0, 0, 0);
        acc[rt][ct] = __builtin_amdgcn_mfma_f32_16x16x32_bf16(al[rt], bh, acc[rt][ct], 0, 0, 0);
      }
    }
    __syncthreads();
  }

  // ---- epilogue: bf16 store, C layout row=(lane>>4)*4+reg, col=lane&15 ----
  #pragma unroll
  for (int rt = 0; rt < 2; rt++){
    #pragma unroll
    for (int reg = 0; reg < 4; reg++){
      int r = m0 + wv * 32 + rt * 16 + q * 4 + reg;
      if (r < M){
        unsigned short* orow = out + (size_t)r * OSTR + colOff + lm;
        #pragma unroll
        for (int ct = 0; ct < BN / 16; ct++)
          orow[ct * 16] = f2bf_rne(acc[rt][ct][reg]);
      }
    }
  }
}

// ---------------- layer-1 attention logits, all 4 heads ----------------
__global__ __launch_bounds__(256) void k_rowdot_all(const unsigned short* __restrict__ xs_all,
                                                    const float* __restrict__ att_src,
                                                    const float* __restrict__ att_dst,
                                                    float* __restrict__ ssrc,
                                                    float* __restrict__ sdst){
  int n = (blockIdx.x * 256 + threadIdx.x) >> 6;
  int lane = threadIdx.x & 63;
  if (n >= NN) return;
  int h = lane >> 4, c8 = lane & 15;
  uint4 u = ((const uint4*)xs_all)[(size_t)n * 64 + lane];
  const float* as = att_src + h * 128 + c8 * 8;
  const float* ad = att_dst + h * 128 + c8 * 8;
  float4 a0 = *(const float4*)as, a1 = *(const float4*)(as + 4);
  float4 b0 = *(const float4*)ad, b1 = *(const float4*)(ad + 4);
  float f[8];
  f[0] = __uint_as_float(u.x << 16); f[1] = __uint_as_float(u.x & 0xffff0000u);
  f[2] = __uint_as_float(u.y << 16); f[3] = __uint_as_float(u.y & 0xffff0000u);
  f[4] = __uint_as_float(u.z << 16); f[5] = __uint_as_float(u.z & 0xffff0000u);
  f[6] = __uint_as_float(u.w << 16); f[7] = __uint_as_float(u.w & 0xffff0000u);
  float d0 = f[0]*a0.x + f[1]*a0.y + f[2]*a0.z + f[3]*a0.w
           + f[4]*a1.x + f[5]*a1.y + f[6]*a1.z + f[7]*a1.w;
  float d1 = f[0]*b0.x + f[1]*b0.y + f[2]*b0.z + f[3]*b0.w
           + f[4]*b1.x + f[5]*b1.y + f[6]*b1.z + f[7]*b1.w;
  #pragma unroll
  for (int off = 1; off < 16; off <<= 1){
    d0 += __shfl_xor(d0, off, 64);
    d1 += __shfl_xor(d1, off, 64);
  }
  if (c8 == 0){ ssrc[n * 4 + h] = d0; sdst[n * 4 + h] = d1; }
}

// ---------------- fused 4-head segment softmax + aggregation ----------------
__global__ __launch_bounds__(256) void k_agg4(const int* __restrict__ rowptr,
                                              const int* __restrict__ csr,
                                              const float* __restrict__ ssrc,
                                              const float* __restrict__ sdst,
                                              const unsigned short* __restrict__ xs_all,
                                              const float* __restrict__ bias,
                                              float* __restrict__ x1){
  int n = (blockIdx.x * 256 + threadIdx.x) >> 6;
  int lane = threadIdx.x & 63;
  if (n >= NN) return;
  int start = rowptr[n], end = rowptr[n + 1];
  float4 sd = ((const float4*)sdst)[n];

  // pass 1: per-head segment max
  float m0 = -3.0e38f, m1 = -3.0e38f, m2 = -3.0e38f, m3 = -3.0e38f;
  for (int e = start + lane; e < end; e += 64){
    float4 sv = ((const float4*)ssrc)[csr[e]];
    m0 = fmaxf(m0, lrelu(sv.x + sd.x));
    m1 = fmaxf(m1, lrelu(sv.y + sd.y));
    m2 = fmaxf(m2, lrelu(sv.z + sd.z));
    m3 = fmaxf(m3, lrelu(sv.w + sd.w));
  }
  #pragma unroll
  for (int off = 32; off; off >>= 1){
    m0 = fmaxf(m0, __shfl_xor(m0, off, 64));
    m1 = fmaxf(m1, __shfl_xor(m1, off, 64));
    m2 = fmaxf(m2, __shfl_xor(m2, off, 64));
    m3 = fmaxf(m3, __shfl_xor(m3, off, 64));
  }

  // pass 2: denominators
  float s0 = 0.f, s1 = 0.f, s2 = 0.f, s3 = 0.f;
  for (int e = start + lane; e < end; e += 64){
    float4 sv = ((const float4*)ssrc)[csr[e]];
    s0 += __expf(lrelu(sv.x + sd.x) - m0);
    s1 += __expf(lrelu(sv.y + sd.y) - m1);
    s2 += __expf(lrelu(sv.z + sd.z) - m2);
    s3 += __expf(lrelu(sv.w + sd.w) - m3);
  }
  #pragma unroll
  for (int off = 32; off; off >>= 1){
    s0 += __shfl_xor(s0, off, 64);
    s1 += __shfl_xor(s1, off, 64);
    s2 += __shfl_xor(s2, off, 64);
    s3 += __shfl_xor(s3, off, 64);
  }
  float i0 = 1.f / s0, i1 = 1.f / s1, i2 = 1.f / s2, i3 = 1.f / s3;

  // pass 3: weighted aggregation, one 1KB row (4 heads x 128 bf16) per edge
  int myh = lane >> 4;
  float acc[8];
  #pragma unroll
  for (int i = 0; i < 8; i++) acc[i] = 0.f;
  for (int cb = start; cb < end; cb += 64){
    int e = cb + lane;
    int sl = 0; float w0 = 0.f, w1 = 0.f, w2 = 0.f, w3 = 0.f;
    if (e < end){
      sl = csr[e];
      float4 sv = ((const float4*)ssrc)[sl];
      w0 = __expf(lrelu(sv.x + sd.x) - m0) * i0;
      w1 = __expf(lrelu(sv.y + sd.y) - m1) * i1;
      w2 = __expf(lrelu(sv.z + sd.z) - m2) * i2;
      w3 = __expf(lrelu(sv.w + sd.w) - m3) * i3;
    }
    int cnt = min(64, end - cb);
    for (int j = 0; j < cnt; j++){
      int s = bcast_i(sl, j);
      float wa = bcast_f(w0, j), wb = bcast_f(w1, j);
      float wc = bcast_f(w2, j), wd = bcast_f(w3, j);
      float wm = (myh == 0) ? wa : (myh == 1) ? wb : (myh == 2) ? wc : wd;
      uint4 u = ((const uint4*)xs_all)[(size_t)s * 64 + lane];
      acc[0] += wm * __uint_as_float(u.x << 16);
      acc[1] += wm * __uint_as_float(u.x & 0xffff0000u);
      acc[2] += wm * __uint_as_float(u.y << 16);
      acc[3] += wm * __uint_as_float(u.y & 0xffff0000u);
      acc[4] += wm * __uint_as_float(u.z << 16);
      acc[5] += wm * __uint_as_float(u.z & 0xffff0000u);
      acc[6] += wm * __uint_as_float(u.w << 16);
      acc[7] += wm * __uint_as_float(u.w & 0xffff0000u);
    }
  }

  const float* bp = bias + lane * 8;
  float4 bb0 = *(const float4*)bp, bb1 = *(const float4*)(bp + 4);
  float o[8];
  o[0] = lrelu(acc[0] + bb0.x); o[1] = lrelu(acc[1] + bb0.y);
  o[2] = lrelu(acc[2] + bb0.z); o[3] = lrelu(acc[3] + bb0.w);
  o[4] = lrelu(acc[4] + bb1.x); o[5] = lrelu(acc[5] + bb1.y);
  o[6] = lrelu(acc[6] + bb1.z); o[7] = lrelu(acc[7] + bb1.w);
  float* op = x1 + (size_t)n * 512 + lane * 8;
  *(float4*)op       = make_float4(o[0], o[1], o[2], o[3]);
  *(float4*)(op + 4) = make_float4(o[4], o[5], o[6], o[7]);
}

// ---------------- layer-2 logits ----------------
__global__ __launch_bounds__(256) void k_rowdot2(const unsigned short* __restrict__ xs2,
                                                 const float* __restrict__ as,
                                                 const float* __restrict__ ad,
                                                 float* __restrict__ ssrc,
                                                 float* __restrict__ sdst){
  int idx = blockIdx.x * 256 + threadIdx.x;
  int n = idx >> 5, sub = idx & 31;
  if (n >= NN) return;
  unsigned int u = ((const unsigned int*)xs2)[n * 32 + sub];
  float f0 = __uint_as_float(u << 16);
  float f1 = __uint_as_float(u & 0xffff0000u);
  float d0 = f0 * as[sub * 2] + f1 * as[sub * 2 + 1];
  float d1 = f0 * ad[sub * 2] + f1 * ad[sub * 2 + 1];
  #pragma unroll
  for (int off = 1; off < 32; off <<= 1){
    d0 += __shfl_xor(d0, off, 64);
    d1 += __shfl_xor(d1, off, 64);
  }
  if (sub == 0){ ssrc[n] = d0; sdst[n] = d1; }
}

// ---------------- layer-2 softmax+agg (2 edges per wave-step) ----------------
__global__ __launch_bounds__(256) void k_agg2(const int* __restrict__ rowptr,
                                              const int* __restrict__ csr,
                                              const float* __restrict__ ssrc,
                                              const float* __restrict__ sdst,
                                              const unsigned short* __restrict__ xs2,
                                              const float* __restrict__ bias,
                                              float* __restrict__ outp){
  int n = (blockIdx.x * 256 + threadIdx.x) >> 6;
  int lane = threadIdx.x & 63;
  if (n >= NN) return;
  int start = rowptr[n], end = rowptr[n + 1];
  float sdn = sdst[n];

  float mloc = -3.0e38f;
  for (int e = start + lane; e < end; e += 64)
    mloc = fmaxf(mloc, lrelu(ssrc[csr[e]] + sdn));
  #pragma unroll
  for (int off = 32; off; off >>= 1) mloc = fmaxf(mloc, __shfl_xor(mloc, off, 64));

  float sloc = 0.f;
  for (int e = start + lane; e < end; e += 64)
    sloc += __expf(lrelu(ssrc[csr[e]] + sdn) - mloc);
  #pragma unroll
  for (int off = 32; off; off >>= 1) sloc += __shfl_xor(sloc, off, 64);
  float inv = 1.f / sloc;

  int half = lane >> 5, sub = lane & 31;
  float acc0 = 0.f, acc1 = 0.f;
  for (int cb = start; cb < end; cb += 64){
    int e = cb + lane;
    int sl = 0; float w = 0.f;
    if (e < end){
      sl = csr[e];
      w = __expf(lrelu(ssrc[sl] + sdn) - mloc) * inv;
    }
    int cnt = min(64, end - cb);
    for (int jj = 0; jj * 2 < cnt; jj++){
      int j0 = jj * 2, j1 = jj * 2 + 1;
      int sa = bcast_i(sl, j0); float wa = bcast_f(w, j0);
      int sb = bcast_i(sl, j1); float wb = bcast_f(w, j1);
      int ss = half ? sb : sa;
      float ws = half ? wb : wa;
      unsigned int u = ((const unsigned int*)xs2)[(size_t)ss * 32 + sub];
      acc0 += ws * __uint_as_float(u << 16);
      acc1 += ws * __uint_as_float(u & 0xffff0000u);
    }
  }
  acc0 += __shfl_xor(acc0, 32, 64);
  acc1 += __shfl_xor(acc1, 32, 64);
  if (lane < 32){
    float o0 = tanhf(lrelu(acc0 + bias[sub * 2]));
    float o1 = tanhf(lrelu(acc1 + bias[sub * 2 + 1]));
    *(float2*)(outp + (size_t)n * 64 + sub * 2) = make_float2(o0, o1);
  }
}

extern "C" void kernel_launch(void* const* d_in, const int* in_sizes, int n_in,
                              void* d_out, int out_size, void* d_ws, size_t ws_size,
                              hipStream_t stream){
  const float* type_emb  = (const float*)d_in[0];
  const int*   edge      = (const int*)d_in[1];
  const float* W         = (const float*)d_in[2];
  const float* att_src   = (const float*)d_in[3];
  const float* att_dst   = (const float*)d_in[4];
  const float* bias      = (const float*)d_in[5];
  const float* W_out     = (const float*)d_in[6];
  const float* att_src_o = (const float*)d_in[7];
  const float* att_dst_o = (const float*)d_in[8];
  const float* bias_o    = (const float*)d_in[9];
  float* out = (float*)d_out;
  (void)in_sizes; (void)n_in; (void)out_size; (void)ws_size;

  char* ws = (char*)d_ws;
  size_t off = 0;
  auto alloc = [&](size_t bytes) -> void* {
    void* p = ws + off;
    off = (off + bytes + 255) & ~(size_t)255;
    return p;
  };
  unsigned short* xs_all = (unsigned short*)alloc((size_t)NN * 512 * 2); // [N][4*128] bf16
  float*          x1     = (float*)alloc((size_t)NN * 512 * 4);          // [N][512] fp32
  unsigned short* xs2    = (unsigned short*)alloc((size_t)NN * 64 * 2);  // [N][64] bf16
  float* ssrc1 = (float*)alloc((size_t)NN * 4 * 4);
  float* sdst1 = (float*)alloc((size_t)NN * 4 * 4);
  float* ssrc2 = (float*)alloc((size_t)NN * 4);
  float* sdst2 = (float*)alloc((size_t)NN * 4);
  int* cnt    = (int*)alloc((size_t)NN * 4);
  int* rowptr = (int*)alloc((size_t)(NN + 1) * 4);
  int* fill   = (int*)alloc((size_t)NN * 4);
  int* csr    = (int*)alloc((size_t)ETOT * 4);
  int* p1     = (int*)alloc((size_t)NSCAN * 4 + 256);
  int* p2     = (int*)alloc((size_t)NSCAN * 4 + 256);
  unsigned short* Bh1 = (unsigned short*)alloc((size_t)4 * 128 * 128 * 2);
  unsigned short* Bl1 = (unsigned short*)alloc((size_t)4 * 128 * 128 * 2);
  unsigned short* Bh2 = (unsigned short*)alloc((size_t)512 * 64 * 2);
  unsigned short* Bl2 = (unsigned short*)alloc((size_t)512 * 64 * 2);

  // ---- CSR build (dst-sorted) ----
  hipMemsetAsync(cnt, 0, (size_t)NN * 4, stream);
  hipMemsetAsync(fill, 0, (size_t)NN * 4, stream);
  k_hist<<<(ETOT + 255) / 256, 256, 0, stream>>>(edge + EE, cnt);
  k_scan1<<<NSCAN, 256, 0, stream>>>(cnt, p1);
  k_scan2<<<1, 64, 0, stream>>>(p1, p2);
  k_scan3<<<NSCAN, 256, 0, stream>>>(cnt, p2, rowptr);
  k_scatter<<<(ETOT + 255) / 256, 256, 0, stream>>>(edge, edge + EE, rowptr, fill, csr);

  // ---- weight conversion ----
  k_convB<<<(4 * 128 * 128 + 255) / 256, 256, 0, stream>>>(W, Bh1, Bl1, 128, 128, 4 * 128 * 128);
  k_convB<<<(512 * 64 + 255) / 256, 256, 0, stream>>>(W_out, Bh2, Bl2, 512, 64, 512 * 64);

  // ---- layer 1: all 4 heads ----
  gemm_split<128, 512><<<dim3(391, 4), 256, 0, stream>>>(type_emb, Bh1, Bl1, xs_all, NN, 128);
  k_rowdot_all<<<12500, 256, 0, stream>>>(xs_all, att_src, att_dst, ssrc1, sdst1);
  k_agg4<<<12500, 256, 0, stream>>>(rowptr, csr, ssrc1, sdst1, xs_all, bias, x1);

  // ---- layer 2 ----
  gemm_split<64, 64><<<dim3(391, 1), 256, 0, stream>>>(x1, Bh2, Bl2, xs2, NN, 512);
  k_rowdot2<<<(NN * 32 + 255) / 256, 256, 0, stream>>>(xs2, att_src_o, att_dst_o, ssrc2, sdst2);
  k_agg2<<<12500, 256, 0, stream>>>(rowptr, csr, ssrc2, sdst2, xs2, bias_o, out);
}